// Round 3
// baseline (174.196 us; speedup 1.0000x reference)
//
#include <hip/hip_runtime.h>
#include <math.h>

namespace {
constexpr int L = 7, S = 200, SE = 240, D = 32, B = 512;
constexpr int NTOK = L * B;               // 3584 tokens
constexpr int NCOMP_BLK = (L * S) / 4;    // 350 compose blocks (wave-per-cluster)
constexpr int GRID = 1024;                // exactly 4 blocks/CU * 256 CU -> all co-resident
constexpr int NROUTE_WAVES = (GRID - NCOMP_BLK) * 4;  // 2696 router waves

// Single fused dispatch.
//  blocks [0, NCOMP_BLK):   compose C[l,s,:] = sum_e w(e) * vec[l,s,e,:]; publish flag[l,s].
//  blocks [NCOMP_BLK, GRID): per wave, 1-2 tokens: logits vs centroids, exact top-3
//    (jax tie-break), softmax, spin on the 3 flags, gather C rows -> out.
// Co-residency is guaranteed: __launch_bounds__(256,4) caps VGPR<=128 so 4 blocks/CU
// always fit (LDS 4.4KB/block), and GRID == 4*256 exactly.
__global__ __launch_bounds__(256, 4) void fused_kernel(
    const float* __restrict__ x,     // [L,B,D]
    const float* __restrict__ vc,    // [L,S,D]
    const float* __restrict__ vec,   // [L,S,SE,D]
    const float* __restrict__ gain,  // [L,S,SE,2]
    const int* __restrict__ blk,     // [L,S,SE,2]
    float* __restrict__ C,           // [L*S, D] ws
    unsigned* __restrict__ flags,    // [L*S] ws, pre-zeroed by memsetAsync
    float* __restrict__ out)         // [L,B,D]
{
  const int wave = threadIdx.x >> 6;
  const int lane = threadIdx.x & 63;

  if (blockIdx.x < NCOMP_BLK) {
    // ---------------- compose: one wave per (l,s) ----------------
    __shared__ float wl[4][SE];
    const int ls = blockIdx.x * 4 + wave;
    for (int e = lane; e < SE; e += 64) {
      const int gi = (ls * SE + e) * 2;
      const float g = gain[gi];
      const int b = blk[gi];
      wl[wave][e] = (b != 0) ? 1.0f / (1.0f + __expf(-g)) : 0.0f;
    }
    __syncthreads();
    const int d4 = lane & 7;   // float4 column [0,8)
    const int eg = lane >> 3;  // e-row group [0,8)
    const float4* v4 = reinterpret_cast<const float4*>(vec) + (size_t)ls * SE * 8;
    float4 acc = make_float4(0.f, 0.f, 0.f, 0.f);
    for (int e0 = 0; e0 < SE; e0 += 8) {  // wave reads 8 rows x 128B = 1KB contiguous
      const int e = e0 + eg;
      const float we = wl[wave][e];
      const float4 v = v4[e * 8 + d4];
      acc.x += we * v.x; acc.y += we * v.y; acc.z += we * v.z; acc.w += we * v.w;
    }
#pragma unroll
    for (int m = 8; m < 64; m <<= 1) {  // reduce over eg (lane bits 3..5)
      acc.x += __shfl_xor(acc.x, m);
      acc.y += __shfl_xor(acc.y, m);
      acc.z += __shfl_xor(acc.z, m);
      acc.w += __shfl_xor(acc.w, m);
    }
    if (eg == 0) reinterpret_cast<float4*>(C + ls * D)[d4] = acc;
    __threadfence();  // make C row visible device-wide before publishing
    if (lane == 0)
      __hip_atomic_store(&flags[ls], 1u, __ATOMIC_RELEASE, __HIP_MEMORY_SCOPE_AGENT);
  } else {
    // ---------------- router + gather: one wave per token (1-2 tokens/wave) ----------------
    __shared__ float xs[4][D];  // wave-private slice; no cross-wave sharing -> no barrier
    const int wid = (blockIdx.x - NCOMP_BLK) * 4 + wave;
    for (int tok = wid; tok < NTOK; tok += NROUTE_WAVES) {
      const int l = tok >> 9;  // B = 512
      if (lane < D) xs[wave][lane] = x[tok * D + lane];

      float v0 = -INFINITY, v1 = -INFINITY, v2 = -INFINITY;
      int i0 = 0x7fffffff, i1 = 0x7fffffff, i2 = 0x7fffffff;
      const float* vcl = vc + l * S * D;
      for (int s = lane; s < S; s += 64) {
        const float4* row = reinterpret_cast<const float4*>(vcl + s * D);
        float dot = 0.f;
#pragma unroll
        for (int q = 0; q < 8; ++q) {
          const float4 r = row[q];
          const float4 xx = reinterpret_cast<const float4*>(xs[wave])[q];
          dot += r.x * xx.x; dot += r.y * xx.y; dot += r.z * xx.z; dot += r.w * xx.w;
        }
        // strict > keeps the earlier (smaller) index on ties; s increases per lane
        if (dot > v0) { v2 = v1; i2 = i1; v1 = v0; i1 = i0; v0 = dot; i0 = s; }
        else if (dot > v1) { v2 = v1; i2 = i1; v1 = dot; i1 = s; }
        else if (dot > v2) { v2 = dot; i2 = s; }
      }
#pragma unroll
      for (int m = 1; m < 64; m <<= 1) {  // butterfly merge of per-lane sorted-3 lists
        const float u0 = __shfl_xor(v0, m);
        const float u1 = __shfl_xor(v1, m);
        const float u2 = __shfl_xor(v2, m);
        const int j0 = __shfl_xor(i0, m);
        const int j1 = __shfl_xor(i1, m);
        const int j2 = __shfl_xor(i2, m);
#pragma unroll
        for (int t = 0; t < 3; ++t) {
          const float u = (t == 0) ? u0 : (t == 1) ? u1 : u2;
          const int j = (t == 0) ? j0 : (t == 1) ? j1 : j2;
          const bool b0 = (u > v0) || (u == v0 && j < i0);
          const bool b1 = (u > v1) || (u == v1 && j < i1);
          const bool b2 = (u > v2) || (u == v2 && j < i2);
          if (b0) { v2 = v1; i2 = i1; v1 = v0; i1 = i0; v0 = u; i0 = j; }
          else if (b1) { v2 = v1; i2 = i1; v1 = u; i1 = j; }
          else if (b2) { v2 = u; i2 = j; }
        }
      }
      const float e1 = __expf(v1 - v0);
      const float e2 = __expf(v2 - v0);
      const float inv = 1.f / (1.f + e1 + e2);
      const float p0 = inv, p1 = e1 * inv, p2 = e2 * inv;

      // wait (usually zero) for the 3 needed C rows
      if (lane < 3) {
        const int idx = (lane == 0) ? i0 : (lane == 1) ? i1 : i2;
        while (__hip_atomic_load(&flags[l * S + idx], __ATOMIC_ACQUIRE,
                                 __HIP_MEMORY_SCOPE_AGENT) == 0u) {
          __builtin_amdgcn_s_sleep(4);
        }
      }
      __threadfence();  // order the C reads after the acquires
      if (lane < D) {
        const float* Cl = C + l * S * D;
        out[tok * D + lane] = p0 * Cl[i0 * D + lane] +
                              p1 * Cl[i1 * D + lane] +
                              p2 * Cl[i2 * D + lane];
      }
    }
  }
}

}  // namespace

extern "C" void kernel_launch(void* const* d_in, const int* in_sizes, int n_in,
                              void* d_out, int out_size, void* d_ws, size_t ws_size,
                              hipStream_t stream) {
  const float* x = (const float*)d_in[0];      // [L,B,D]
  const float* vc = (const float*)d_in[1];     // [L,S,D]
  const float* vec = (const float*)d_in[2];    // [L,S,SE,D]
  const float* gain = (const float*)d_in[3];   // [L,S,SE,2]
  const int* blk = (const int*)d_in[4];        // [L,S,SE,2]
  float* out = (float*)d_out;                  // [L,B,D]

  char* ws = (char*)d_ws;
  float* C = (float*)ws;                          // 179,200 B
  unsigned* flags = (unsigned*)(ws + 179200);     // 5,600 B

  hipMemsetAsync(flags, 0, L * S * sizeof(unsigned), stream);
  fused_kernel<<<GRID, 256, 0, stream>>>(x, vc, vec, gain, blk, C, flags, out);
}

// Round 4
// 30.567 us; speedup vs baseline: 5.6987x; 5.6987x over previous
//
#include <hip/hip_runtime.h>
#include <math.h>

namespace {
constexpr int L = 7, S = 200, SE = 240, D = 32, B = 512;
constexpr int NTOK = L * B;      // 3584
constexpr int NCLUST = L * S;    // 1400

// ---------- kernel 1: compose. One block (256 thr) per cluster. ----------
// C[ls,d] = sum_e sigmoid(gain[ls,e,0]) * (blk[ls,e,0]!=0) * vec[ls,e,d]
// Balanced: 1400 blocks spread over all 256 CUs (~5.5 blocks/CU), 30KB/block.
__global__ __launch_bounds__(256) void compose_kernel(
    const float* __restrict__ vec,   // [L,S,SE,D]
    const float* __restrict__ gain,  // [L,S,SE,2]
    const int* __restrict__ blk,     // [L,S,SE,2]
    float* __restrict__ C)           // [L*S, D]
{
  const int ls = blockIdx.x;
  const int tid = threadIdx.x;
  __shared__ float sw[SE];
  __shared__ float4 red[32][9];  // pad 8->9 float4s: row-stride 36 banks, conflict-free
  if (tid < SE) {
    const int gi = (ls * SE + tid) * 2;
    const float g = gain[gi];
    const int b = blk[gi];
    sw[tid] = (b != 0) ? 1.0f / (1.0f + __expf(-g)) : 0.0f;
  }
  __syncthreads();
  const int d4 = tid & 7;   // float4 column [0,8)
  const int er = tid >> 3;  // row group [0,32)
  const float4* v4 = reinterpret_cast<const float4*>(vec) + (size_t)ls * SE * 8;
  float4 acc = make_float4(0.f, 0.f, 0.f, 0.f);
#pragma unroll
  for (int k = 0; k < 7; ++k) {  // rows er, er+32, ..., er+192 (each wave: 8 rows x 128B)
    const int e = er + 32 * k;
    const float we = sw[e];
    const float4 v = v4[e * 8 + d4];
    acc.x += we * v.x; acc.y += we * v.y; acc.z += we * v.z; acc.w += we * v.w;
  }
  if (er < 16) {  // tail rows 224..239
    const int e = 224 + er;
    const float we = sw[e];
    const float4 v = v4[e * 8 + d4];
    acc.x += we * v.x; acc.y += we * v.y; acc.z += we * v.z; acc.w += we * v.w;
  }
  red[er][d4] = acc;
  __syncthreads();
  if (tid < 64) {  // wave0 finishes: 4-way in-thread sum + 3-step shfl tree over g
    const int dd = tid & 7;   // float4 column
    const int g = tid >> 3;   // [0,8)
    float4 a = red[g][dd];
    const float4 b1 = red[g + 8][dd];
    const float4 b2 = red[g + 16][dd];
    const float4 b3 = red[g + 24][dd];
    a.x += b1.x + b2.x + b3.x;
    a.y += b1.y + b2.y + b3.y;
    a.z += b1.z + b2.z + b3.z;
    a.w += b1.w + b2.w + b3.w;
#pragma unroll
    for (int m = 8; m < 64; m <<= 1) {  // reduce over g (lane bits 3..5)
      a.x += __shfl_xor(a.x, m);
      a.y += __shfl_xor(a.y, m);
      a.z += __shfl_xor(a.z, m);
      a.w += __shfl_xor(a.w, m);
    }
    if (tid < 8) reinterpret_cast<float4*>(C + ls * D)[tid] = a;
  }
}

// ---------- kernel 2: route + gather. One wave per token, no LDS, no barriers. ----------
// Dot layout: 64 lanes = 8 rows (r8) x 8 float4-cols (q). Each s0-step reads 8
// consecutive centroid rows as one contiguous 1KB wave-load, partial dot per lane,
// 3-step shfl reduce over q -> q==0 lanes hold full dots for rows s0+r8.
__global__ __launch_bounds__(256) void route_kernel(
    const float* __restrict__ x,   // [L,B,D]
    const float* __restrict__ vc,  // [L,S,D]
    const float* __restrict__ C,   // [L*S, D]
    float* __restrict__ out)       // [L,B,D]
{
  const int wave = threadIdx.x >> 6;
  const int lane = threadIdx.x & 63;
  const int tok = blockIdx.x * 4 + wave;  // grid 896 * 4 waves = 3584 exactly
  const int l = tok >> 9;                 // B = 512
  const int q = lane & 7;
  const int r8 = lane >> 3;

  const float4 xq = reinterpret_cast<const float4*>(x + tok * D)[q];  // broadcast line
  const float* vcl = vc + l * S * D;

  float v0 = -INFINITY, v1 = -INFINITY, v2 = -INFINITY;
  int i0 = 0x7fffffff, i1 = 0x7fffffff, i2 = 0x7fffffff;
  for (int s0 = 0; s0 < S; s0 += 8) {  // 25 iterations, 200 = 25*8 exact
    const int row = s0 + r8;
    const float4 v = reinterpret_cast<const float4*>(vcl + row * D)[q];
    float part = v.x * xq.x + v.y * xq.y + v.z * xq.z + v.w * xq.w;
    part += __shfl_xor(part, 1);
    part += __shfl_xor(part, 2);
    part += __shfl_xor(part, 4);
    if (q == 0) {  // strict > keeps earlier (smaller) index; row increases per lane
      if (part > v0) { v2 = v1; i2 = i1; v1 = v0; i1 = i0; v0 = part; i0 = row; }
      else if (part > v1) { v2 = v1; i2 = i1; v1 = part; i1 = row; }
      else if (part > v2) { v2 = part; i2 = row; }
    }
  }
#pragma unroll
  for (int m = 1; m < 64; m <<= 1) {  // butterfly merge (jax tie-break: desc val, low idx)
    const float u0 = __shfl_xor(v0, m);
    const float u1 = __shfl_xor(v1, m);
    const float u2 = __shfl_xor(v2, m);
    const int j0 = __shfl_xor(i0, m);
    const int j1 = __shfl_xor(i1, m);
    const int j2 = __shfl_xor(i2, m);
#pragma unroll
    for (int t = 0; t < 3; ++t) {
      const float u = (t == 0) ? u0 : (t == 1) ? u1 : u2;
      const int j = (t == 0) ? j0 : (t == 1) ? j1 : j2;
      const bool b0 = (u > v0) || (u == v0 && j < i0);
      const bool b1 = (u > v1) || (u == v1 && j < i1);
      const bool b2 = (u > v2) || (u == v2 && j < i2);
      if (b0) { v2 = v1; i2 = i1; v1 = v0; i1 = i0; v0 = u; i0 = j; }
      else if (b1) { v2 = v1; i2 = i1; v1 = u; i1 = j; }
      else if (b2) { v2 = u; i2 = j; }
    }
  }
  const float e1 = __expf(v1 - v0);
  const float e2 = __expf(v2 - v0);
  const float inv = 1.f / (1.f + e1 + e2);
  const float p0 = inv, p1 = e1 * inv, p2 = e2 * inv;

  if (lane < D) {
    const float* Cl = C + l * S * D;
    out[tok * D + lane] = p0 * Cl[i0 * D + lane] +
                          p1 * Cl[i1 * D + lane] +
                          p2 * Cl[i2 * D + lane];
  }
}

}  // namespace

extern "C" void kernel_launch(void* const* d_in, const int* in_sizes, int n_in,
                              void* d_out, int out_size, void* d_ws, size_t ws_size,
                              hipStream_t stream) {
  const float* x = (const float*)d_in[0];      // [L,B,D]
  const float* vc = (const float*)d_in[1];     // [L,S,D]
  const float* vec = (const float*)d_in[2];    // [L,S,SE,D]
  const float* gain = (const float*)d_in[3];   // [L,S,SE,2]
  const int* blk = (const int*)d_in[4];        // [L,S,SE,2]
  float* out = (float*)d_out;                  // [L,B,D]
  float* C = (float*)d_ws;                     // L*S*D floats = 179,200 B

  compose_kernel<<<NCLUST, 256, 0, stream>>>(vec, gain, blk, C);
  route_kernel<<<NTOK / 4, 256, 0, stream>>>(x, vc, C, out);
}